// Round 21
// baseline (50.813 us; speedup 1.0000x reference)
//
#include <hip/hip_runtime.h>

#define SUBS  64
#define GUARD 256              // left guard halves (32 tiles) [fallback path]
#define LB    32               // IIR block length (rows per run/wave)
#define JT    8                // history terms: 8*32 = 256 >= 200-tap support
#define LSTR  136              // k_mm LDS row stride (halves)

typedef _Float16 f16x8 __attribute__((ext_vector_type(8)));
typedef float    f32x4 __attribute__((ext_vector_type(4)));

union uh2 { uint u; _Float16 h[2]; };

__device__ inline f16x8 ld_frag(const float* p) {
    float4 a = *(const float4*)p;
    float4 b = *(const float4*)(p + 4);
    f16x8 f;
    f[0]=(_Float16)a.x; f[1]=(_Float16)a.y; f[2]=(_Float16)a.z; f[3]=(_Float16)a.w;
    f[4]=(_Float16)b.x; f[5]=(_Float16)b.y; f[6]=(_Float16)b.z; f[7]=(_Float16)b.w;
    return f;
}
__device__ inline uint pkh2(float a, float b) {
    union { _Float16 h[2]; uint u; } p;
    p.h[0] = (_Float16)a; p.h[1] = (_Float16)b; return p.u;
}

// IIR core: per basis, z[m] = 2r z[m-1] - r^2 z[m-2] + cr*x[m-1]
#define STEP3(u)                                                                 \
    _Pragma("unroll")                                                            \
    for (int b = 0; b < 3; ++b) {                                                \
        const float yn = fmaf(twr[b], y1[b], fmaf(mr2[b], y2[b], cr[b] * (u)));  \
        y2[b] = y1[b]; y1[b] = yn;                                               \
    }
#define PAIRW(wrd) {                                                             \
    uh2 w_; w_.u = (wrd);                                                        \
    STEP3((float)w_.h[0]);                                                       \
    STEP3((float)w_.h[1]); }

// ---------------------------------------------------------------------------
// Kernel 1 (unchanged — measured ~15 us): MFMA Zc, Yc into transposed tiled
// layout [tile][64 s][8 halves]; fused from-rest 32-step state run per wave
// -> packed fb[run][lane][8]. Tail tiles zero-filled.
// ---------------------------------------------------------------------------
__global__ __launch_bounds__(256, 4) void k_mm(
    const float* __restrict__ Z, const float* __restrict__ Y,
    const float* __restrict__ C,
    const float* __restrict__ K_spike, const float* __restrict__ tau_spike,
    const float* __restrict__ delta_spike,
    _Float16* __restrict__ Zt, _Float16* __restrict__ Yt,
    float* __restrict__ fb, int T, int rgz, int NB)
{
    __shared__ _Float16 ztl[SUBS * LSTR];
    __shared__ _Float16 ytl[SUBS * LSTR];
    const int tid  = threadIdx.x;
    const int lane = tid & 63;
    const int wv   = tid >> 6;
    const int lr   = lane & 15;
    const int lg   = lane >> 4;
    const int t0b  = blockIdx.x * 128;

    int dl = (int)rintf(delta_spike[lane]);
    dl = min(max(dl, 0), 30);
    const bool alldl0 = __all(dl == 0);

    if (blockIdx.x == 0) {                    // fb guard runs (-8..-1)
        for (int idx = tid; idx < JT * 512; idx += 256) fb[idx] = 0.f;
    }
    if (!alldl0) {                            // guards only for fallback path
        if (blockIdx.x < 8) {
            const int tile = blockIdx.x * 4 + wv;
            uint4 z4 = {0, 0, 0, 0};
            ((uint4*)Zt)[(size_t)tile * 64 + lane] = z4;
            ((uint4*)Yt)[(size_t)tile * 64 + lane] = z4;
        } else if (blockIdx.x < 18) {
            const int tile = rgz + (blockIdx.x - 8) * 4 + wv;
            uint4 z4 = {0, 0, 0, 0};
            ((uint4*)Zt)[(size_t)tile * 64 + lane] = z4;
            ((uint4*)Yt)[(size_t)tile * 64 + lane] = z4;
        }
    }

    f16x8 bfr[4][2];
    #pragma unroll
    for (int nt = 0; nt < 4; ++nt)
        #pragma unroll
        for (int ks = 0; ks < 2; ++ks)
            bfr[nt][ks] = ld_frag(&C[(lr + 16 * nt) * 64 + ks * 32 + lg * 8]);

    #pragma unroll
    for (int g = 0; g < 2; ++g) {
        const int t0 = t0b + wv * 32 + g * 16;
        const int rowA = t0 + lr;
        const bool okA = rowA < T;
        f16x8 az[2], ay[2];
        #pragma unroll
        for (int ks = 0; ks < 2; ++ks) {
            if (okA) {
                az[ks] = ld_frag(&Z[(size_t)rowA * 64 + ks * 32 + lg * 8]);
                ay[ks] = ld_frag(&Y[(size_t)rowA * 64 + ks * 32 + lg * 8]);
            } else {
                az[ks] = (f16x8)(_Float16)0.f;
                ay[ks] = (f16x8)(_Float16)0.f;
            }
        }

        f32x4 accZ[4], accY[4];
        #pragma unroll
        for (int nt = 0; nt < 4; ++nt) { accZ[nt] = (f32x4){0,0,0,0}; accY[nt] = (f32x4){0,0,0,0}; }
        #pragma unroll
        for (int nt = 0; nt < 4; ++nt) {
            #pragma unroll
            for (int ks = 0; ks < 2; ++ks) {
                accZ[nt] = __builtin_amdgcn_mfma_f32_16x16x32_f16(az[ks], bfr[nt][ks], accZ[nt], 0, 0, 0);
                accY[nt] = __builtin_amdgcn_mfma_f32_16x16x32_f16(ay[ks], bfr[nt][ks], accY[nt], 0, 0, 0);
            }
        }

        #pragma unroll
        for (int nt = 0; nt < 4; ++nt) {
            const int sc = lr + 16 * nt;
            const int lt = wv * 32 + g * 16 + lg * 4;
            uint2 pz, py;
            pz.x = pkh2(accZ[nt][0], accZ[nt][1]);
            pz.y = pkh2(accZ[nt][2], accZ[nt][3]);
            py.x = pkh2(accY[nt][0], accY[nt][1]);
            py.y = pkh2(accY[nt][2], accY[nt][3]);
            *(uint2*)&ztl[sc * LSTR + lt] = pz;
            *(uint2*)&ytl[sc * LSTR + lt] = py;
        }
    }

    __syncthreads();

    // fused from-rest state run first (serial chain overlaps store latency)
    const int grun = blockIdx.x * 4 + wv;
    if (grun < NB) {
        float twr[3], mr2[3], cr[3];
        #pragma unroll
        for (int b = 0; b < 3; ++b) {
            const float tau = __expf(tau_spike[b]);
            const float r   = __expf(-1.0f / tau);
            twr[b] = 2.0f * r;
            mr2[b] = -r * r;
            cr[b]  = K_spike[lane * 3 + b] / tau * r;
        }
        const uint* zr = (const uint*)ztl + lane * (LSTR / 2) + wv * 16;
        float y1[3] = {0.f, 0.f, 0.f}, y2[3] = {0.f, 0.f, 0.f};
        #pragma unroll
        for (int k = 0; k < 16; ++k) PAIRW(zr[k]);
        float* fout = fb + (size_t)(grun + JT) * 512 + lane * 8;
        *(float4*)fout       = make_float4(y1[0], y2[0], y1[1], y2[1]);
        *(float2*)(fout + 4) = make_float2(y1[2], y2[2]);
    }

    // cooperative tiled stores (row = s fastest -> coalesced); tail zero-fill
    const int gbase = (GUARD >> 3) + blockIdx.x * 16;
    #pragma unroll
    for (int it = 0; it < 4; ++it) {
        const int chunk = it * 256 + tid;
        const int row = chunk & 63;
        const int col = chunk >> 6;
        const int tb  = t0b + col * 8;
        if (tb + 7 < T) {
            ((uint4*)Zt)[(size_t)(gbase + col) * 64 + row] =
                *(const uint4*)&ztl[row * LSTR + col * 8];
            ((uint4*)Yt)[(size_t)(gbase + col) * 64 + row] =
                *(const uint4*)&ytl[row * LSTR + col * 8];
        } else {
            union { ushort u[8]; uint4 v; } vz, vy;
            #pragma unroll
            for (int h = 0; h < 8; ++h) {
                const bool ok = (tb + h < T);
                vz.u[h] = ok ? ((const ushort*)ztl)[row * LSTR + col * 8 + h] : (ushort)0;
                vy.u[h] = ok ? ((const ushort*)ytl)[row * LSTR + col * 8 + h] : (ushort)0;
            }
            ((uint4*)Zt)[(size_t)(gbase + col) * 64 + row] = vz.v;
            ((uint4*)Yt)[(size_t)(gbase + col) * 64 + row] = vy.v;
        }
    }
}

// ---------------------------------------------------------------------------
// Kernel 2 (slim, R17 shape — measured ~8.7 us): Horner-compose v[32i] from
// packed fb, 30 steps over 4 aligned x tiles; writes pre[t][s] = Yc + filt
// (f16). NO S / theta / sigmoid here (R17/R19 anomaly: S loads in a compute
// kernel cost 20-30 us; quarantined into k_sig).
// ---------------------------------------------------------------------------
#define PREW(o, yh, f) {                                                         \
    const int t_ = t0 + (o);                                                     \
    if (t_ < T) pre[(size_t)t_ * 64 + s] = (_Float16)((float)(yh) + (f));        \
    }

#define PW(xwrd, ywrd, ob) {                                                     \
    uh2 wx_, wy_;                                                                \
    wx_.u = (xwrd); wy_.u = (ywrd);                                              \
    STEP3((float)wx_.h[0]);                                                      \
    PREW((ob),     wy_.h[0], y1[0] + y1[1] + y1[2]);                             \
    STEP3((float)wx_.h[1]);                                                      \
    PREW((ob) + 1, wy_.h[1], y1[0] + y1[1] + y1[2]); }

__global__ __launch_bounds__(256, 4) void k_iir2(
    const _Float16* __restrict__ Zt, const _Float16* __restrict__ Yt,
    const float* __restrict__ K_spike, const float* __restrict__ tau_spike,
    const float* __restrict__ delta_spike,
    const float* __restrict__ fb, _Float16* __restrict__ pre, int T, int NB)
{
    const int tid = threadIdx.x;
    const int s   = tid & 63;
    const int wv  = tid >> 6;
    const int i   = blockIdx.x * 4 + wv;
    if (i >= NB) return;
    const int t0 = i * LB;

    float twr[3], mr2[3], cr[3], taus[3];
    #pragma unroll
    for (int b = 0; b < 3; ++b) {
        const float tau = __expf(tau_spike[b]);
        taus[b] = tau;
        const float r = __expf(-1.0f / tau);
        twr[b] = 2.0f * r;
        mr2[b] = -r * r;
        cr[b]  = K_spike[s * 3 + b] / tau * r;
    }
    int dl = (int)rintf(delta_spike[s]);
    dl = min(max(dl, 0), 30);

    if (__all(dl == 0) && (t0 + LB <= T)) {
        // M^32 per basis: z[n+k] = (k+1) r^k z[n] - k r^(k+1) z[n-1]
        float aL[3], bL[3], cL[3], dL[3];
        #pragma unroll
        for (int b = 0; b < 3; ++b) {
            const float r   = 0.5f * twr[b];
            const float rm1 = __expf(-(float)(LB - 1) / taus[b]);  // r^31
            const float rl  = rm1 * r;                             // r^32
            const float rp  = rl * r;                              // r^33
            aL[b] = (float)(LB + 1) * rl;
            bL[b] = -(float)LB * rp;
            cL[b] = (float)LB * rm1;
            dL[b] = -(float)(LB - 1) * rl;
        }
        float y1[3], y2[3];
        {   // f_{i-8}
            const float* fq = fb + (size_t)i * 512 + s * 8;
            const float4 lo = *(const float4*)fq;
            const float2 hi = *(const float2*)(fq + 4);
            y1[0] = lo.x; y2[0] = lo.y; y1[1] = lo.z; y2[1] = lo.w;
            y1[2] = hi.x; y2[2] = hi.y;
        }
        #pragma unroll
        for (int j = 7; j >= 1; --j) {
            const float* fq = fb + (size_t)(i + JT - j) * 512 + s * 8;
            const float4 lo = *(const float4*)fq;
            const float2 hi = *(const float2*)(fq + 4);
            float n1, n2;
            n1 = fmaf(aL[0], y1[0], fmaf(bL[0], y2[0], lo.x));
            n2 = fmaf(cL[0], y1[0], fmaf(dL[0], y2[0], lo.y));
            y1[0] = n1; y2[0] = n2;
            n1 = fmaf(aL[1], y1[1], fmaf(bL[1], y2[1], lo.z));
            n2 = fmaf(cL[1], y1[1], fmaf(dL[1], y2[1], lo.w));
            y1[1] = n1; y2[1] = n2;
            n1 = fmaf(aL[2], y1[2], fmaf(bL[2], y2[2], hi.x));
            n2 = fmaf(cL[2], y1[2], fmaf(dL[2], y2[2], hi.y));
            y1[2] = n1; y2[2] = n2;
        }

        const uint4* xb = (const uint4*)Zt + (size_t)(32 + 4 * i) * 64 + s;
        const uint4 x0 = xb[0], x1 = xb[64], x2 = xb[128], x3 = xb[192];
        const uint4* yb = (const uint4*)Yt + (size_t)(32 + 4 * i) * 64 + s;
        const uint4 yv0 = yb[0], yv1 = yb[64], yv2 = yb[128], yv3 = yb[192];

        {   // outputs 0,1 from the composed state (word 0)
            uh2 wy_; wy_.u = yv0.x;
            PREW(0, wy_.h[0], y2[0] + y2[1] + y2[2]);
            PREW(1, wy_.h[1], y1[0] + y1[1] + y1[2]);
        }
        PW(x0.x, yv0.y,  2);  PW(x0.y, yv0.z,  4);
        PW(x0.z, yv0.w,  6);  PW(x0.w, yv1.x,  8);
        PW(x1.x, yv1.y, 10);  PW(x1.y, yv1.z, 12);
        PW(x1.z, yv1.w, 14);  PW(x1.w, yv2.x, 16);
        PW(x2.x, yv2.y, 18);  PW(x2.y, yv2.z, 20);
        PW(x2.z, yv2.w, 22);  PW(x2.w, yv3.x, 24);
        PW(x3.x, yv3.y, 26);  PW(x3.y, yv3.z, 28);
        PW(x3.z, yv3.w, 30);
    } else {
        // generic per-lane-delay path: also writes pre (k_sig finishes it)
        float y1[3] = {0.f, 0.f, 0.f}, y2[3] = {0.f, 0.f, 0.f};
        const int xi0 = t0 - 226 - dl;
        for (int k = 0; k < 224 + LB; ++k) {
            const int h = GUARD + xi0 + k;
            const float u = (float)Zt[(size_t)(h >> 3) * 512 + s * 8 + (h & 7)];
            STEP3(u);
            const int o = k - 224;
            if (o >= 0) {
                const int t = t0 + o;
                if (t < T) {
                    const int hy = GUARD + t;
                    const float yc = (float)Yt[(size_t)(hy >> 3) * 512 + s * 8 + (hy & 7)];
                    pre[(size_t)t * 64 + s] = (_Float16)(yc + y1[0] + y1[1] + y1[2]);
                }
            }
        }
    }
}

// ---------------------------------------------------------------------------
// Kernel 3 (pure streaming epilogue): out = sigmoid(pre + S + theta)*W + Vo.
// 8 elements/thread: uint4 pre (8 f16), 2x float4 S, 2x float4 out.
// W/theta staged in LDS. Grid-stride at 2048 blocks.
// ---------------------------------------------------------------------------
__global__ __launch_bounds__(256) void k_sig(
    const _Float16* __restrict__ pre, const float* __restrict__ S,
    const float* __restrict__ theta, const float* __restrict__ W,
    const float* __restrict__ Vo, float* __restrict__ out, int n8)
{
    __shared__ float wls[SUBS], tls[SUBS];
    if (threadIdx.x < SUBS) {
        wls[threadIdx.x] = W[threadIdx.x];
        tls[threadIdx.x] = theta[threadIdx.x];
    }
    __syncthreads();
    const float vo = Vo[0];

    for (int c = blockIdx.x * 256 + threadIdx.x; c < n8; c += gridDim.x * 256) {
        const size_t base = (size_t)c * 8;
        const uint4  pv = *(const uint4*)(pre + base);
        const float4 s0 = *(const float4*)(S + base);
        const float4 s1 = *(const float4*)(S + base + 4);
        const int sb = (int)(base & 63);          // multiple of 8; sb+7 <= 63

        uh2 p0, p1, p2, p3;
        p0.u = pv.x; p1.u = pv.y; p2.u = pv.z; p3.u = pv.w;

        float4 o0, o1;
        #define SIG1(ph, sv, thj, wj, dst) {                                     \
            const float xin = (float)(ph) + (sv) + tls[sb + (thj)];              \
            const float sg  = 1.0f / (1.0f + __expf(-xin));                      \
            dst = fmaf(sg, wls[sb + (wj)], vo); }
        SIG1(p0.h[0], s0.x, 0, 0, o0.x);
        SIG1(p0.h[1], s0.y, 1, 1, o0.y);
        SIG1(p1.h[0], s0.z, 2, 2, o0.z);
        SIG1(p1.h[1], s0.w, 3, 3, o0.w);
        SIG1(p2.h[0], s1.x, 4, 4, o1.x);
        SIG1(p2.h[1], s1.y, 5, 5, o1.y);
        SIG1(p3.h[0], s1.z, 6, 6, o1.z);
        SIG1(p3.h[1], s1.w, 7, 7, o1.w);
        #undef SIG1

        *(float4*)(out + base)     = o0;
        *(float4*)(out + base + 4) = o1;
    }
}

// ---------------------------------------------------------------------------
extern "C" void kernel_launch(void* const* d_in, const int* in_sizes, int n_in,
                              void* d_out, int out_size, void* d_ws, size_t ws_size,
                              hipStream_t stream)
{
    const float* S     = (const float*)d_in[0];
    const float* Y     = (const float*)d_in[1];
    const float* Z     = (const float*)d_in[2];
    const float* C     = (const float*)d_in[3];
    const float* Vo    = (const float*)d_in[4];
    const float* W     = (const float*)d_in[5];
    const float* theta = (const float*)d_in[6];
    const float* K     = (const float*)d_in[7];
    const float* tau   = (const float*)d_in[8];
    const float* delta = (const float*)d_in[9];
    const int T  = in_sizes[0] / SUBS;
    const int NB = (T + LB - 1) / LB;

    const int rgz    = (GUARD + T + 7) >> 3;
    const int ntiles = rgz + 44;
    _Float16* Zt  = (_Float16*)d_ws;
    _Float16* Yt  = (_Float16*)((char*)d_ws + (size_t)ntiles * 1024);
    float*    fb  = (float*)((char*)d_ws + (size_t)ntiles * 2048);
    _Float16* pre = (_Float16*)((char*)d_ws + (size_t)ntiles * 2048
                                + (size_t)(NB + JT + 4) * 2048);

    k_mm<<<(T + 127) / 128, 256, 0, stream>>>(Z, Y, C, K, tau, delta,
                                              Zt, Yt, fb, T, rgz, NB);
    k_iir2<<<(NB + 3) / 4, 256, 0, stream>>>(Zt, Yt, K, tau, delta, fb, pre, T, NB);
    const int n8 = (T * SUBS) / 8;
    k_sig<<<2048, 256, 0, stream>>>(pre, S, theta, W, Vo, (float*)d_out, n8);
}

// Round 22
// 48.573 us; speedup vs baseline: 1.0461x; 1.0461x over previous
//
#include <hip/hip_runtime.h>

#define SUBS  64
#define GUARD 256              // left guard halves (32 tiles) [fallback path]
#define LB    32               // IIR block length (rows per run/wave)
#define JT    8                // history terms: 8*32 = 256 >= 200-tap support
#define LSTR  136              // k_mm LDS row stride (halves)

typedef _Float16 f16x8 __attribute__((ext_vector_type(8)));
typedef float    f32x4 __attribute__((ext_vector_type(4)));

union uh2 { uint u; _Float16 h[2]; };

__device__ inline f16x8 ld_frag(const float* p) {
    float4 a = *(const float4*)p;
    float4 b = *(const float4*)(p + 4);
    f16x8 f;
    f[0]=(_Float16)a.x; f[1]=(_Float16)a.y; f[2]=(_Float16)a.z; f[3]=(_Float16)a.w;
    f[4]=(_Float16)b.x; f[5]=(_Float16)b.y; f[6]=(_Float16)b.z; f[7]=(_Float16)b.w;
    return f;
}
__device__ inline uint pkh2(float a, float b) {
    union { _Float16 h[2]; uint u; } p;
    p.h[0] = (_Float16)a; p.h[1] = (_Float16)b; return p.u;
}

// IIR core: per basis, z[m] = 2r z[m-1] - r^2 z[m-2] + cr*x[m-1]
#define STEP3(u)                                                                 \
    _Pragma("unroll")                                                            \
    for (int b = 0; b < 3; ++b) {                                                \
        const float yn = fmaf(twr[b], y1[b], fmaf(mr2[b], y2[b], cr[b] * (u)));  \
        y2[b] = y1[b]; y1[b] = yn;                                               \
    }
#define PAIRW(wrd) {                                                             \
    uh2 w_; w_.u = (wrd);                                                        \
    STEP3((float)w_.h[0]);                                                       \
    STEP3((float)w_.h[1]); }

// ---------------------------------------------------------------------------
// Kernel 1 (unchanged — ~15 us): MFMA Zc, Yc into transposed tiled layout
// [tile][64 s][8 halves]; fused from-rest 32-step state run per wave ->
// packed fb[run][lane][8]. Tail tiles zero-filled.
// ---------------------------------------------------------------------------
__global__ __launch_bounds__(256, 4) void k_mm(
    const float* __restrict__ Z, const float* __restrict__ Y,
    const float* __restrict__ C,
    const float* __restrict__ K_spike, const float* __restrict__ tau_spike,
    const float* __restrict__ delta_spike,
    _Float16* __restrict__ Zt, _Float16* __restrict__ Yt,
    float* __restrict__ fb, int T, int rgz, int NB)
{
    __shared__ _Float16 ztl[SUBS * LSTR];
    __shared__ _Float16 ytl[SUBS * LSTR];
    const int tid  = threadIdx.x;
    const int lane = tid & 63;
    const int wv   = tid >> 6;
    const int lr   = lane & 15;
    const int lg   = lane >> 4;
    const int t0b  = blockIdx.x * 128;

    int dl = (int)rintf(delta_spike[lane]);
    dl = min(max(dl, 0), 30);
    const bool alldl0 = __all(dl == 0);

    if (blockIdx.x == 0) {                    // fb guard runs (-8..-1)
        for (int idx = tid; idx < JT * 512; idx += 256) fb[idx] = 0.f;
    }
    if (!alldl0) {                            // guards only for fallback path
        if (blockIdx.x < 8) {
            const int tile = blockIdx.x * 4 + wv;
            uint4 z4 = {0, 0, 0, 0};
            ((uint4*)Zt)[(size_t)tile * 64 + lane] = z4;
            ((uint4*)Yt)[(size_t)tile * 64 + lane] = z4;
        } else if (blockIdx.x < 18) {
            const int tile = rgz + (blockIdx.x - 8) * 4 + wv;
            uint4 z4 = {0, 0, 0, 0};
            ((uint4*)Zt)[(size_t)tile * 64 + lane] = z4;
            ((uint4*)Yt)[(size_t)tile * 64 + lane] = z4;
        }
    }

    f16x8 bfr[4][2];
    #pragma unroll
    for (int nt = 0; nt < 4; ++nt)
        #pragma unroll
        for (int ks = 0; ks < 2; ++ks)
            bfr[nt][ks] = ld_frag(&C[(lr + 16 * nt) * 64 + ks * 32 + lg * 8]);

    #pragma unroll
    for (int g = 0; g < 2; ++g) {
        const int t0 = t0b + wv * 32 + g * 16;
        const int rowA = t0 + lr;
        const bool okA = rowA < T;
        f16x8 az[2], ay[2];
        #pragma unroll
        for (int ks = 0; ks < 2; ++ks) {
            if (okA) {
                az[ks] = ld_frag(&Z[(size_t)rowA * 64 + ks * 32 + lg * 8]);
                ay[ks] = ld_frag(&Y[(size_t)rowA * 64 + ks * 32 + lg * 8]);
            } else {
                az[ks] = (f16x8)(_Float16)0.f;
                ay[ks] = (f16x8)(_Float16)0.f;
            }
        }

        f32x4 accZ[4], accY[4];
        #pragma unroll
        for (int nt = 0; nt < 4; ++nt) { accZ[nt] = (f32x4){0,0,0,0}; accY[nt] = (f32x4){0,0,0,0}; }
        #pragma unroll
        for (int nt = 0; nt < 4; ++nt) {
            #pragma unroll
            for (int ks = 0; ks < 2; ++ks) {
                accZ[nt] = __builtin_amdgcn_mfma_f32_16x16x32_f16(az[ks], bfr[nt][ks], accZ[nt], 0, 0, 0);
                accY[nt] = __builtin_amdgcn_mfma_f32_16x16x32_f16(ay[ks], bfr[nt][ks], accY[nt], 0, 0, 0);
            }
        }

        #pragma unroll
        for (int nt = 0; nt < 4; ++nt) {
            const int sc = lr + 16 * nt;
            const int lt = wv * 32 + g * 16 + lg * 4;
            uint2 pz, py;
            pz.x = pkh2(accZ[nt][0], accZ[nt][1]);
            pz.y = pkh2(accZ[nt][2], accZ[nt][3]);
            py.x = pkh2(accY[nt][0], accY[nt][1]);
            py.y = pkh2(accY[nt][2], accY[nt][3]);
            *(uint2*)&ztl[sc * LSTR + lt] = pz;
            *(uint2*)&ytl[sc * LSTR + lt] = py;
        }
    }

    __syncthreads();

    // fused from-rest state run first (serial chain overlaps store latency)
    const int grun = blockIdx.x * 4 + wv;
    if (grun < NB) {
        float twr[3], mr2[3], cr[3];
        #pragma unroll
        for (int b = 0; b < 3; ++b) {
            const float tau = __expf(tau_spike[b]);
            const float r   = __expf(-1.0f / tau);
            twr[b] = 2.0f * r;
            mr2[b] = -r * r;
            cr[b]  = K_spike[lane * 3 + b] / tau * r;
        }
        const uint* zr = (const uint*)ztl + lane * (LSTR / 2) + wv * 16;
        float y1[3] = {0.f, 0.f, 0.f}, y2[3] = {0.f, 0.f, 0.f};
        #pragma unroll
        for (int k = 0; k < 16; ++k) PAIRW(zr[k]);
        float* fout = fb + (size_t)(grun + JT) * 512 + lane * 8;
        *(float4*)fout       = make_float4(y1[0], y2[0], y1[1], y2[1]);
        *(float2*)(fout + 4) = make_float2(y1[2], y2[2]);
    }

    // cooperative tiled stores (row = s fastest -> coalesced); tail zero-fill
    const int gbase = (GUARD >> 3) + blockIdx.x * 16;
    #pragma unroll
    for (int it = 0; it < 4; ++it) {
        const int chunk = it * 256 + tid;
        const int row = chunk & 63;
        const int col = chunk >> 6;
        const int tb  = t0b + col * 8;
        if (tb + 7 < T) {
            ((uint4*)Zt)[(size_t)(gbase + col) * 64 + row] =
                *(const uint4*)&ztl[row * LSTR + col * 8];
            ((uint4*)Yt)[(size_t)(gbase + col) * 64 + row] =
                *(const uint4*)&ytl[row * LSTR + col * 8];
        } else {
            union { ushort u[8]; uint4 v; } vz, vy;
            #pragma unroll
            for (int h = 0; h < 8; ++h) {
                const bool ok = (tb + h < T);
                vz.u[h] = ok ? ((const ushort*)ztl)[row * LSTR + col * 8 + h] : (ushort)0;
                vy.u[h] = ok ? ((const ushort*)ytl)[row * LSTR + col * 8 + h] : (ushort)0;
            }
            ((uint4*)Zt)[(size_t)(gbase + col) * 64 + row] = vz.v;
            ((uint4*)Yt)[(size_t)(gbase + col) * 64 + row] = vy.v;
        }
    }
}

// ---------------------------------------------------------------------------
// Kernel 2: block stages 12 contiguous fb entries (24 KB) into LDS once
// (covers all 4 runs' Horner windows: global idx [i0, i0+11], local
// wv+8-j for j=1..8). x/y tile loads issued BEFORE S-pack so the barrier's
// drain is one joint wait. Then Horner (from LDS), 30 steps, sigmoid emit.
// ---------------------------------------------------------------------------
#define OUTP(o, yh, ph, f) {                                                     \
    const int t_ = t0 + (o);                                                     \
    if (t_ < T) {                                                                \
        const float xin_ = (float)(yh) + (float)(ph) + (f);                      \
        const float sig_ = 1.0f / (1.0f + __expf(-xin_));                        \
        out[(size_t)t_ * 64 + s] = fmaf(sig_, wsub, vo);                         \
    } }

#define PW(xwrd, ywrd, swrd, ob) {                                               \
    uh2 wx_, wy_, wp_;                                                           \
    wx_.u = (xwrd); wy_.u = (ywrd); wp_.u = (swrd);                              \
    STEP3((float)wx_.h[0]);                                                      \
    OUTP((ob),     wy_.h[0], wp_.h[0], y1[0] + y1[1] + y1[2]);                   \
    STEP3((float)wx_.h[1]);                                                      \
    OUTP((ob) + 1, wy_.h[1], wp_.h[1], y1[0] + y1[1] + y1[2]); }

__global__ __launch_bounds__(256, 3) void k_iir2(
    const _Float16* __restrict__ Zt, const _Float16* __restrict__ Yt,
    const float* __restrict__ S,
    const float* __restrict__ K_spike, const float* __restrict__ tau_spike,
    const float* __restrict__ delta_spike, const float* __restrict__ theta,
    const float* __restrict__ W, const float* __restrict__ Vo,
    const float* __restrict__ fb, float* __restrict__ out, int T, int NB)
{
    __shared__ float flb[12 * 512];           // 24 KB: fb entries [i0, i0+11]
    const int tid = threadIdx.x;
    const int s   = tid & 63;
    const int wv  = tid >> 6;
    const int i0  = blockIdx.x * 4;
    const int i   = i0 + wv;
    const int ic  = min(i, NB - 1);
    const int t0  = i * LB;
    const int t0c = ic * LB;                  // clamped for hoisted loads

    // ---- 1) issue fb staging loads (gate the barrier; first in flight)
    float4 g0, g1, g2, g3, g4, g5;
    {
        const float4* fbg = (const float4*)(fb + (size_t)i0 * 512);
        g0 = fbg[tid];         g1 = fbg[tid + 256];
        g2 = fbg[tid + 512];   g3 = fbg[tid + 768];
        g4 = fbg[tid + 1024];  g5 = fbg[tid + 1280];
    }

    // ---- 2) issue x / Yc tile loads (consumed after Horner)
    const uint4* xb = (const uint4*)Zt + (size_t)(32 + 4 * ic) * 64 + s;
    const uint4 x0 = xb[0], x1 = xb[64], x2 = xb[128], x3 = xb[192];
    const uint4* yb = (const uint4*)Yt + (size_t)(32 + 4 * ic) * 64 + s;
    const uint4 yv0 = yb[0], yv1 = yb[64], yv2 = yb[128], yv3 = yb[192];

    // ---- 3) S + theta pack (coalesced 256B rows)
    const float th = theta[s];
    const float* spp = S + (size_t)t0c * 64 + s;
    uint4 sp0, sp1, sp2, sp3;
    sp0.x = pkh2(spp[   0] + th, spp[  64] + th);
    sp0.y = pkh2(spp[ 128] + th, spp[ 192] + th);
    sp0.z = pkh2(spp[ 256] + th, spp[ 320] + th);
    sp0.w = pkh2(spp[ 384] + th, spp[ 448] + th);
    sp1.x = pkh2(spp[ 512] + th, spp[ 576] + th);
    sp1.y = pkh2(spp[ 640] + th, spp[ 704] + th);
    sp1.z = pkh2(spp[ 768] + th, spp[ 832] + th);
    sp1.w = pkh2(spp[ 896] + th, spp[ 960] + th);
    sp2.x = pkh2(spp[1024] + th, spp[1088] + th);
    sp2.y = pkh2(spp[1152] + th, spp[1216] + th);
    sp2.z = pkh2(spp[1280] + th, spp[1344] + th);
    sp2.w = pkh2(spp[1408] + th, spp[1472] + th);
    sp3.x = pkh2(spp[1536] + th, spp[1600] + th);
    sp3.y = pkh2(spp[1664] + th, spp[1728] + th);
    sp3.z = pkh2(spp[1792] + th, spp[1856] + th);
    sp3.w = pkh2(spp[1920] + th, spp[1984] + th);

    // ---- 4) write staging to LDS, barrier (all waves participate)
    {
        float4* fl4 = (float4*)flb;
        fl4[tid]        = g0;  fl4[tid + 256]  = g1;
        fl4[tid + 512]  = g2;  fl4[tid + 768]  = g3;
        fl4[tid + 1024] = g4;  fl4[tid + 1280] = g5;
    }
    __syncthreads();

    // ---- IIR coefficients
    float twr[3], mr2[3], cr[3], taus[3];
    #pragma unroll
    for (int b = 0; b < 3; ++b) {
        const float tau = __expf(tau_spike[b]);
        taus[b] = tau;
        const float r = __expf(-1.0f / tau);
        twr[b] = 2.0f * r;
        mr2[b] = -r * r;
        cr[b]  = K_spike[s * 3 + b] / tau * r;
    }
    int dl = (int)rintf(delta_spike[s]);
    dl = min(max(dl, 0), 30);
    const float wsub = W[s];
    const float vo   = Vo[0];

    if (i < NB && __all(dl == 0) && (t0 + LB <= T)) {
        // M^32 per basis: z[n+k] = (k+1) r^k z[n] - k r^(k+1) z[n-1]
        float aL[3], bL[3], cL[3], dL[3];
        #pragma unroll
        for (int b = 0; b < 3; ++b) {
            const float r   = 0.5f * twr[b];
            const float rm1 = __expf(-(float)(LB - 1) / taus[b]);  // r^31
            const float rl  = rm1 * r;                             // r^32
            const float rp  = rl * r;                              // r^33
            aL[b] = (float)(LB + 1) * rl;
            bL[b] = -(float)LB * rp;
            cL[b] = (float)LB * rm1;
            dL[b] = -(float)(LB - 1) * rl;
        }
        float y1[3], y2[3];
        {   // f_{i-8} at local entry wv
            const float* fq = flb + wv * 512 + s * 8;
            const float4 lo = *(const float4*)fq;
            const float2 hi = *(const float2*)(fq + 4);
            y1[0] = lo.x; y2[0] = lo.y; y1[1] = lo.z; y2[1] = lo.w;
            y1[2] = hi.x; y2[2] = hi.y;
        }
        #pragma unroll
        for (int j = 7; j >= 1; --j) {        // local entry wv+8-j
            const float* fq = flb + (wv + 8 - j) * 512 + s * 8;
            const float4 lo = *(const float4*)fq;
            const float2 hi = *(const float2*)(fq + 4);
            float n1, n2;
            n1 = fmaf(aL[0], y1[0], fmaf(bL[0], y2[0], lo.x));
            n2 = fmaf(cL[0], y1[0], fmaf(dL[0], y2[0], lo.y));
            y1[0] = n1; y2[0] = n2;
            n1 = fmaf(aL[1], y1[1], fmaf(bL[1], y2[1], lo.z));
            n2 = fmaf(cL[1], y1[1], fmaf(dL[1], y2[1], lo.w));
            y1[1] = n1; y2[1] = n2;
            n1 = fmaf(aL[2], y1[2], fmaf(bL[2], y2[2], hi.x));
            n2 = fmaf(cL[2], y1[2], fmaf(dL[2], y2[2], hi.y));
            y1[2] = n1; y2[2] = n2;
        }

        {   // outputs 0,1 from the composed state (word 0)
            uh2 wy_, wp_;
            wy_.u = yv0.x; wp_.u = sp0.x;
            OUTP(0, wy_.h[0], wp_.h[0], y2[0] + y2[1] + y2[2]);
            OUTP(1, wy_.h[1], wp_.h[1], y1[0] + y1[1] + y1[2]);
        }
        PW(x0.x, yv0.y, sp0.y,  2);  PW(x0.y, yv0.z, sp0.z,  4);
        PW(x0.z, yv0.w, sp0.w,  6);  PW(x0.w, yv1.x, sp1.x,  8);
        PW(x1.x, yv1.y, sp1.y, 10);  PW(x1.y, yv1.z, sp1.z, 12);
        PW(x1.z, yv1.w, sp1.w, 14);  PW(x1.w, yv2.x, sp2.x, 16);
        PW(x2.x, yv2.y, sp2.y, 18);  PW(x2.y, yv2.z, sp2.z, 20);
        PW(x2.z, yv2.w, sp2.w, 22);  PW(x2.w, yv3.x, sp3.x, 24);
        PW(x3.x, yv3.y, sp3.y, 26);  PW(x3.y, yv3.z, sp3.z, 28);
        PW(x3.z, yv3.w, sp3.w, 30);
    } else if (i < NB) {
        // generic per-lane-delay path (correct, slow; unused for bench data)
        float y1[3] = {0.f, 0.f, 0.f}, y2[3] = {0.f, 0.f, 0.f};
        const int xi0 = t0 - 226 - dl;
        for (int k = 0; k < 224 + LB; ++k) {
            const int h = GUARD + xi0 + k;
            const float u = (float)Zt[(size_t)(h >> 3) * 512 + s * 8 + (h & 7)];
            STEP3(u);
            const int o = k - 224;
            if (o >= 0) {
                const int t = t0 + o;
                if (t < T) {
                    const int hy = GUARD + t;
                    const float yc = (float)Yt[(size_t)(hy >> 3) * 512 + s * 8 + (hy & 7)];
                    const float xin = yc + S[(size_t)t * 64 + s] + th
                                      + y1[0] + y1[1] + y1[2];
                    const float sig = 1.0f / (1.0f + __expf(-xin));
                    out[(size_t)t * 64 + s] = fmaf(sig, wsub, vo);
                }
            }
        }
    }
}

// ---------------------------------------------------------------------------
extern "C" void kernel_launch(void* const* d_in, const int* in_sizes, int n_in,
                              void* d_out, int out_size, void* d_ws, size_t ws_size,
                              hipStream_t stream)
{
    const float* S     = (const float*)d_in[0];
    const float* Y     = (const float*)d_in[1];
    const float* Z     = (const float*)d_in[2];
    const float* C     = (const float*)d_in[3];
    const float* Vo    = (const float*)d_in[4];
    const float* W     = (const float*)d_in[5];
    const float* theta = (const float*)d_in[6];
    const float* K     = (const float*)d_in[7];
    const float* tau   = (const float*)d_in[8];
    const float* delta = (const float*)d_in[9];
    const int T  = in_sizes[0] / SUBS;
    const int NB = (T + LB - 1) / LB;

    const int rgz    = (GUARD + T + 7) >> 3;
    const int ntiles = rgz + 44;
    _Float16* Zt = (_Float16*)d_ws;
    _Float16* Yt = (_Float16*)((char*)d_ws + (size_t)ntiles * 1024);
    float*    fb = (float*)((char*)d_ws + (size_t)ntiles * 2048);

    k_mm<<<(T + 127) / 128, 256, 0, stream>>>(Z, Y, C, K, tau, delta,
                                              Zt, Yt, fb, T, rgz, NB);
    k_iir2<<<(NB + 3) / 4, 256, 0, stream>>>(Zt, Yt, S, K, tau, delta, theta,
                                             W, Vo, fb, (float*)d_out, T, NB);
}

// Round 23
// 48.464 us; speedup vs baseline: 1.0485x; 1.0022x over previous
//
#include <hip/hip_runtime.h>

#define SUBS  64
#define GUARD 256              // left guard halves (32 tiles) [fallback path]
#define LB    32               // IIR block length (rows per run)
#define JT    8                // history terms: 8*32 = 256 >= 200-tap support
#define LSTR  136              // k_mm LDS row stride (halves)

typedef _Float16 f16x8 __attribute__((ext_vector_type(8)));
typedef float    f32x4 __attribute__((ext_vector_type(4)));

union uh2 { uint u; _Float16 h[2]; };

__device__ inline f16x8 ld_frag(const float* p) {
    float4 a = *(const float4*)p;
    float4 b = *(const float4*)(p + 4);
    f16x8 f;
    f[0]=(_Float16)a.x; f[1]=(_Float16)a.y; f[2]=(_Float16)a.z; f[3]=(_Float16)a.w;
    f[4]=(_Float16)b.x; f[5]=(_Float16)b.y; f[6]=(_Float16)b.z; f[7]=(_Float16)b.w;
    return f;
}
__device__ inline uint pkh2(float a, float b) {
    union { _Float16 h[2]; uint u; } p;
    p.h[0] = (_Float16)a; p.h[1] = (_Float16)b; return p.u;
}

// IIR core: per basis, z[m] = 2r z[m-1] - r^2 z[m-2] + cr*x[m-1]
#define STEP3(u)                                                                 \
    _Pragma("unroll")                                                            \
    for (int b = 0; b < 3; ++b) {                                                \
        const float yn = fmaf(twr[b], y1[b], fmaf(mr2[b], y2[b], cr[b] * (u)));  \
        y2[b] = y1[b]; y1[b] = yn;                                               \
    }
#define PAIRW(wrd) {                                                             \
    uh2 w_; w_.u = (wrd);                                                        \
    STEP3((float)w_.h[0]);                                                       \
    STEP3((float)w_.h[1]); }

// ---------------------------------------------------------------------------
// Kernel 1 (~15 us): MFMA Zc, Yc into transposed tiled layout
// [tile][64 s][8 halves]; fused from-rest 32-step state run per wave with a
// MID-RUN SNAPSHOT: g_i = state after 16 steps (gb), f_i = final (fb).
// Tail tiles zero-filled.
// ---------------------------------------------------------------------------
__global__ __launch_bounds__(256, 4) void k_mm(
    const float* __restrict__ Z, const float* __restrict__ Y,
    const float* __restrict__ C,
    const float* __restrict__ K_spike, const float* __restrict__ tau_spike,
    const float* __restrict__ delta_spike,
    _Float16* __restrict__ Zt, _Float16* __restrict__ Yt,
    float* __restrict__ fb, float* __restrict__ gb, int T, int rgz, int NB)
{
    __shared__ _Float16 ztl[SUBS * LSTR];
    __shared__ _Float16 ytl[SUBS * LSTR];
    const int tid  = threadIdx.x;
    const int lane = tid & 63;
    const int wv   = tid >> 6;
    const int lr   = lane & 15;
    const int lg   = lane >> 4;
    const int t0b  = blockIdx.x * 128;

    int dl = (int)rintf(delta_spike[lane]);
    dl = min(max(dl, 0), 30);
    const bool alldl0 = __all(dl == 0);

    if (blockIdx.x == 0) {                    // fb guard runs (-8..-1)
        for (int idx = tid; idx < JT * 512; idx += 256) fb[idx] = 0.f;
    }
    if (!alldl0) {                            // guards only for fallback path
        if (blockIdx.x < 8) {
            const int tile = blockIdx.x * 4 + wv;
            uint4 z4 = {0, 0, 0, 0};
            ((uint4*)Zt)[(size_t)tile * 64 + lane] = z4;
            ((uint4*)Yt)[(size_t)tile * 64 + lane] = z4;
        } else if (blockIdx.x < 18) {
            const int tile = rgz + (blockIdx.x - 8) * 4 + wv;
            uint4 z4 = {0, 0, 0, 0};
            ((uint4*)Zt)[(size_t)tile * 64 + lane] = z4;
            ((uint4*)Yt)[(size_t)tile * 64 + lane] = z4;
        }
    }

    f16x8 bfr[4][2];
    #pragma unroll
    for (int nt = 0; nt < 4; ++nt)
        #pragma unroll
        for (int ks = 0; ks < 2; ++ks)
            bfr[nt][ks] = ld_frag(&C[(lr + 16 * nt) * 64 + ks * 32 + lg * 8]);

    #pragma unroll
    for (int g = 0; g < 2; ++g) {
        const int t0 = t0b + wv * 32 + g * 16;
        const int rowA = t0 + lr;
        const bool okA = rowA < T;
        f16x8 az[2], ay[2];
        #pragma unroll
        for (int ks = 0; ks < 2; ++ks) {
            if (okA) {
                az[ks] = ld_frag(&Z[(size_t)rowA * 64 + ks * 32 + lg * 8]);
                ay[ks] = ld_frag(&Y[(size_t)rowA * 64 + ks * 32 + lg * 8]);
            } else {
                az[ks] = (f16x8)(_Float16)0.f;
                ay[ks] = (f16x8)(_Float16)0.f;
            }
        }

        f32x4 accZ[4], accY[4];
        #pragma unroll
        for (int nt = 0; nt < 4; ++nt) { accZ[nt] = (f32x4){0,0,0,0}; accY[nt] = (f32x4){0,0,0,0}; }
        #pragma unroll
        for (int nt = 0; nt < 4; ++nt) {
            #pragma unroll
            for (int ks = 0; ks < 2; ++ks) {
                accZ[nt] = __builtin_amdgcn_mfma_f32_16x16x32_f16(az[ks], bfr[nt][ks], accZ[nt], 0, 0, 0);
                accY[nt] = __builtin_amdgcn_mfma_f32_16x16x32_f16(ay[ks], bfr[nt][ks], accY[nt], 0, 0, 0);
            }
        }

        #pragma unroll
        for (int nt = 0; nt < 4; ++nt) {
            const int sc = lr + 16 * nt;
            const int lt = wv * 32 + g * 16 + lg * 4;
            uint2 pz, py;
            pz.x = pkh2(accZ[nt][0], accZ[nt][1]);
            pz.y = pkh2(accZ[nt][2], accZ[nt][3]);
            py.x = pkh2(accY[nt][0], accY[nt][1]);
            py.y = pkh2(accY[nt][2], accY[nt][3]);
            *(uint2*)&ztl[sc * LSTR + lt] = pz;
            *(uint2*)&ytl[sc * LSTR + lt] = py;
        }
    }

    __syncthreads();

    // fused from-rest state run with mid-run snapshot
    const int grun = blockIdx.x * 4 + wv;
    if (grun < NB) {
        float twr[3], mr2[3], cr[3];
        #pragma unroll
        for (int b = 0; b < 3; ++b) {
            const float tau = __expf(tau_spike[b]);
            const float r   = __expf(-1.0f / tau);
            twr[b] = 2.0f * r;
            mr2[b] = -r * r;
            cr[b]  = K_spike[lane * 3 + b] / tau * r;
        }
        const uint* zr = (const uint*)ztl + lane * (LSTR / 2) + wv * 16;
        float y1[3] = {0.f, 0.f, 0.f}, y2[3] = {0.f, 0.f, 0.f};
        #pragma unroll
        for (int k = 0; k < 8; ++k) PAIRW(zr[k]);
        float* gout = gb + (size_t)grun * 512 + lane * 8;   // 16-step snapshot
        *(float4*)gout       = make_float4(y1[0], y2[0], y1[1], y2[1]);
        *(float2*)(gout + 4) = make_float2(y1[2], y2[2]);
        #pragma unroll
        for (int k = 8; k < 16; ++k) PAIRW(zr[k]);
        float* fout = fb + (size_t)(grun + JT) * 512 + lane * 8;
        *(float4*)fout       = make_float4(y1[0], y2[0], y1[1], y2[1]);
        *(float2*)(fout + 4) = make_float2(y1[2], y2[2]);
    }

    // cooperative tiled stores (row = s fastest -> coalesced); tail zero-fill
    const int gbase = (GUARD >> 3) + blockIdx.x * 16;
    #pragma unroll
    for (int it = 0; it < 4; ++it) {
        const int chunk = it * 256 + tid;
        const int row = chunk & 63;
        const int col = chunk >> 6;
        const int tb  = t0b + col * 8;
        if (tb + 7 < T) {
            ((uint4*)Zt)[(size_t)(gbase + col) * 64 + row] =
                *(const uint4*)&ztl[row * LSTR + col * 8];
            ((uint4*)Yt)[(size_t)(gbase + col) * 64 + row] =
                *(const uint4*)&ytl[row * LSTR + col * 8];
        } else {
            union { ushort u[8]; uint4 v; } vz, vy;
            #pragma unroll
            for (int h = 0; h < 8; ++h) {
                const bool ok = (tb + h < T);
                vz.u[h] = ok ? ((const ushort*)ztl)[row * LSTR + col * 8 + h] : (ushort)0;
                vy.u[h] = ok ? ((const ushort*)ytl)[row * LSTR + col * 8 + h] : (ushort)0;
            }
            ((uint4*)Zt)[(size_t)(gbase + col) * 64 + row] = vz.v;
            ((uint4*)Yt)[(size_t)(gbase + col) * 64 + row] = vy.v;
        }
    }
}

// ---------------------------------------------------------------------------
// Kernel 2 (half-runs): wave (i, h) emits outputs [32i+16h, +16).
//  h=0: v = Horner over f_{i-8..i-1} (v = (z[32i], z[32i-1]));
//  h=1: v16 = M^16 * v + g_i  (z[n+16] = 17 r^16 z[n] - 16 r^17 z[n-1];
//       z[n+15] = 16 r^15 z[n] - 15 r^16 z[n-1]; g_i = 16-step from-rest).
// Then 2 direct emits + 14 steps (7 x-words). 2x waves, half serial chain.
// ---------------------------------------------------------------------------
#define OUTP(o, yh, ph, f) {                                                     \
    const int t_ = t0 + (o);                                                     \
    if (t_ < T) {                                                                \
        const float xin_ = (float)(yh) + (float)(ph) + (f);                      \
        const float sig_ = 1.0f / (1.0f + __expf(-xin_));                        \
        out[(size_t)t_ * 64 + s] = fmaf(sig_, wsub, vo);                         \
    } }

#define PW(xwrd, ywrd, swrd, ob) {                                               \
    uh2 wx_, wy_, wp_;                                                           \
    wx_.u = (xwrd); wy_.u = (ywrd); wp_.u = (swrd);                              \
    STEP3((float)wx_.h[0]);                                                      \
    OUTP((ob),     wy_.h[0], wp_.h[0], y1[0] + y1[1] + y1[2]);                   \
    STEP3((float)wx_.h[1]);                                                      \
    OUTP((ob) + 1, wy_.h[1], wp_.h[1], y1[0] + y1[1] + y1[2]); }

__global__ __launch_bounds__(256, 3) void k_iir2(
    const _Float16* __restrict__ Zt, const _Float16* __restrict__ Yt,
    const float* __restrict__ S,
    const float* __restrict__ K_spike, const float* __restrict__ tau_spike,
    const float* __restrict__ delta_spike, const float* __restrict__ theta,
    const float* __restrict__ W, const float* __restrict__ Vo,
    const float* __restrict__ fb, const float* __restrict__ gb,
    float* __restrict__ out, int T, int NB)
{
    const int tid = threadIdx.x;
    const int s   = tid & 63;
    const int wv  = tid >> 6;
    const int gid = blockIdx.x * 4 + wv;      // 0 .. 2*NB-1
    const int i   = gid >> 1;
    const int hf  = gid & 1;
    if (i >= NB) return;
    const int t0 = i * LB + 16 * hf;

    float twr[3], mr2[3], cr[3], taus[3];
    #pragma unroll
    for (int b = 0; b < 3; ++b) {
        const float tau = __expf(tau_spike[b]);
        taus[b] = tau;
        const float r = __expf(-1.0f / tau);
        twr[b] = 2.0f * r;
        mr2[b] = -r * r;
        cr[b]  = K_spike[s * 3 + b] / tau * r;
    }
    int dl = (int)rintf(delta_spike[s]);
    dl = min(max(dl, 0), 30);
    const float th   = theta[s];
    const float wsub = W[s];
    const float vo   = Vo[0];

    if (__all(dl == 0) && ((i + 1) * LB <= T)) {
        // ---- hoisted tile loads (2 x-tiles, 2 y-tiles for this half)
        const int tb = 32 + 4 * i + 2 * hf;
        const uint4* xb = (const uint4*)Zt + (size_t)tb * 64 + s;
        const uint4 xA = xb[0], xB = xb[64];
        const uint4* yb = (const uint4*)Yt + (size_t)tb * 64 + s;
        const uint4 yA = yb[0], yB = yb[64];

        // ---- S + theta pack (8 words = 16 rows)
        const float* spp = S + (size_t)t0 * 64 + s;
        uint4 spA, spB;
        spA.x = pkh2(spp[  0] + th, spp[ 64] + th);
        spA.y = pkh2(spp[128] + th, spp[192] + th);
        spA.z = pkh2(spp[256] + th, spp[320] + th);
        spA.w = pkh2(spp[384] + th, spp[448] + th);
        spB.x = pkh2(spp[512] + th, spp[576] + th);
        spB.y = pkh2(spp[640] + th, spp[704] + th);
        spB.z = pkh2(spp[768] + th, spp[832] + th);
        spB.w = pkh2(spp[896] + th, spp[960] + th);

        // ---- Horner compose v[32i] from f_{i-8..i-1}
        float aL[3], bL[3], cL[3], dL[3];
        #pragma unroll
        for (int b = 0; b < 3; ++b) {
            const float r   = 0.5f * twr[b];
            const float rm1 = __expf(-(float)(LB - 1) / taus[b]);  // r^31
            const float rl  = rm1 * r;                             // r^32
            const float rp  = rl * r;                              // r^33
            aL[b] = (float)(LB + 1) * rl;
            bL[b] = -(float)LB * rp;
            cL[b] = (float)LB * rm1;
            dL[b] = -(float)(LB - 1) * rl;
        }
        float y1[3], y2[3];
        {   // f_{i-8}
            const float* fq = fb + (size_t)i * 512 + s * 8;
            const float4 lo = *(const float4*)fq;
            const float2 hi = *(const float2*)(fq + 4);
            y1[0] = lo.x; y2[0] = lo.y; y1[1] = lo.z; y2[1] = lo.w;
            y1[2] = hi.x; y2[2] = hi.y;
        }
        #pragma unroll
        for (int j = 7; j >= 1; --j) {
            const float* fq = fb + (size_t)(i + JT - j) * 512 + s * 8;
            const float4 lo = *(const float4*)fq;
            const float2 hi = *(const float2*)(fq + 4);
            float n1, n2;
            n1 = fmaf(aL[0], y1[0], fmaf(bL[0], y2[0], lo.x));
            n2 = fmaf(cL[0], y1[0], fmaf(dL[0], y2[0], lo.y));
            y1[0] = n1; y2[0] = n2;
            n1 = fmaf(aL[1], y1[1], fmaf(bL[1], y2[1], lo.z));
            n2 = fmaf(cL[1], y1[1], fmaf(dL[1], y2[1], lo.w));
            y1[1] = n1; y2[1] = n2;
            n1 = fmaf(aL[2], y1[2], fmaf(bL[2], y2[2], hi.x));
            n2 = fmaf(cL[2], y1[2], fmaf(dL[2], y2[2], hi.y));
            y1[2] = n1; y2[2] = n2;
        }

        // ---- h=1: advance 16 steps via closed-form M^16 + from-rest g_i
        if (hf) {
            const float* gq = gb + (size_t)i * 512 + s * 8;
            const float4 glo = *(const float4*)gq;
            const float2 ghi = *(const float2*)(gq + 4);
            const float g1[3] = { glo.x, glo.z, ghi.x };
            const float g2[3] = { glo.y, glo.w, ghi.y };
            #pragma unroll
            for (int b = 0; b < 3; ++b) {
                const float r   = 0.5f * twr[b];
                const float r15 = __expf(-15.0f / taus[b]);
                const float r16 = r15 * r;
                const float r17 = r16 * r;
                const float n1 = fmaf(17.0f * r16, y1[b],
                                 fmaf(-16.0f * r17, y2[b], g1[b]));
                const float n2 = fmaf(16.0f * r15, y1[b],
                                 fmaf(-15.0f * r16, y2[b], g2[b]));
                y1[b] = n1; y2[b] = n2;
            }
        }

        // ---- emits: 2 direct from state, then 14 steps (7 x-words)
        {
            uh2 wy_, wp_;
            wy_.u = yA.x; wp_.u = spA.x;
            OUTP(0, wy_.h[0], wp_.h[0], y2[0] + y2[1] + y2[2]);
            OUTP(1, wy_.h[1], wp_.h[1], y1[0] + y1[1] + y1[2]);
        }
        PW(xA.x, yA.y, spA.y,  2);  PW(xA.y, yA.z, spA.z,  4);
        PW(xA.z, yA.w, spA.w,  6);  PW(xA.w, yB.x, spB.x,  8);
        PW(xB.x, yB.y, spB.y, 10);  PW(xB.y, yB.z, spB.z, 12);
        PW(xB.z, yB.w, spB.w, 14);
    } else if (hf == 0) {
        // generic per-lane-delay path (h=0 wave does the whole run)
        float y1[3] = {0.f, 0.f, 0.f}, y2[3] = {0.f, 0.f, 0.f};
        const int bt0 = i * LB;
        const int xi0 = bt0 - 226 - dl;
        for (int k = 0; k < 224 + LB; ++k) {
            const int h = GUARD + xi0 + k;
            const float u = (float)Zt[(size_t)(h >> 3) * 512 + s * 8 + (h & 7)];
            STEP3(u);
            const int o = k - 224;
            if (o >= 0) {
                const int t = bt0 + o;
                if (t < T) {
                    const int hy = GUARD + t;
                    const float yc = (float)Yt[(size_t)(hy >> 3) * 512 + s * 8 + (hy & 7)];
                    const float xin = yc + S[(size_t)t * 64 + s] + th
                                      + y1[0] + y1[1] + y1[2];
                    const float sig = 1.0f / (1.0f + __expf(-xin));
                    out[(size_t)t * 64 + s] = fmaf(sig, wsub, vo);
                }
            }
        }
    }
}

// ---------------------------------------------------------------------------
extern "C" void kernel_launch(void* const* d_in, const int* in_sizes, int n_in,
                              void* d_out, int out_size, void* d_ws, size_t ws_size,
                              hipStream_t stream)
{
    const float* S     = (const float*)d_in[0];
    const float* Y     = (const float*)d_in[1];
    const float* Z     = (const float*)d_in[2];
    const float* C     = (const float*)d_in[3];
    const float* Vo    = (const float*)d_in[4];
    const float* W     = (const float*)d_in[5];
    const float* theta = (const float*)d_in[6];
    const float* K     = (const float*)d_in[7];
    const float* tau   = (const float*)d_in[8];
    const float* delta = (const float*)d_in[9];
    const int T  = in_sizes[0] / SUBS;
    const int NB = (T + LB - 1) / LB;

    const int rgz    = (GUARD + T + 7) >> 3;
    const int ntiles = rgz + 44;
    _Float16* Zt = (_Float16*)d_ws;
    _Float16* Yt = (_Float16*)((char*)d_ws + (size_t)ntiles * 1024);
    float*    fb = (float*)((char*)d_ws + (size_t)ntiles * 2048);
    float*    gb = (float*)((char*)d_ws + (size_t)ntiles * 2048
                            + (size_t)(NB + JT + 4) * 2048);

    k_mm<<<(T + 127) / 128, 256, 0, stream>>>(Z, Y, C, K, tau, delta,
                                              Zt, Yt, fb, gb, T, rgz, NB);
    k_iir2<<<(2 * NB + 3) / 4, 256, 0, stream>>>(Zt, Yt, S, K, tau, delta, theta,
                                                 W, Vo, fb, gb,
                                                 (float*)d_out, T, NB);
}